// Round 1
// baseline (549.273 us; speedup 1.0000x reference)
//
#include <hip/hip_runtime.h>
#include <math.h>

#define NN 4096
#define KK 32
#define KOb 32
#define BB 2

constexpr float EPS = 1e-6f;

// ---- workspace layout (in float elements) ----
#define WS_VALS   0                         // B*N*K floats
#define WS_IDX    (WS_VALS + BB*NN*KK)      // B*N*K ints
#define WS_HB     (WS_IDX + BB*NN*KK)       // B*KO
#define WS_WSOFT  (WS_HB + BB*KOb)          // B*KO
#define WS_WMEAN  (WS_WSOFT + BB*KOb)       // KO
#define WS_A1     (WS_WMEAN + KOb)          // B*N*K
#define WS_M      (WS_A1 + BB*NN*KK)        // B*N
#define WS_CHI    (WS_M + BB*NN)            // B*N*K
#define WS_A2     (WS_CHI + BB*NN*KK)       // B*N*K (dense-normalized edge vals)
#define WS_SEV    (WS_A2 + BB*NN*KK)        // B*N
#define WS_TEV    (WS_SEV + BB*NN)          // B*N  (atomic accum, must be zeroed)
#define WS_Q      (WS_TEV + BB*NN)          // B*N

// ---- output layout (float elements) ----
#define OUT_A2   0
#define OUT_U    ((size_t)BB*NN*NN)
#define OUT_PSRC (OUT_U + BB*NN)
#define OUT_PTGT (OUT_PSRC + BB*NN)
#define OUT_MAP  (OUT_PTGT + BB*NN)

// =====================================================================
// K1: per-row top-32 via LDS argmax extraction. 1 block (256 thr) / row.
// Order within k doesn't matter downstream (all k-reductions are
// order-independent sums / softmaxes), only the SET of top-32.
// =====================================================================
__global__ __launch_bounds__(256) void k_topk(const float* __restrict__ A0,
                                              float* __restrict__ ws) {
    __shared__ float sv[NN];
    __shared__ float red_v[4];
    __shared__ int   red_i[4];
    __shared__ int   win_i;

    const int R = blockIdx.x;                  // global row in [0, B*N)
    const float* row = A0 + (size_t)R * NN;
    const int t = threadIdx.x;

    for (int j = t; j < NN; j += 256) sv[j] = row[j];
    __syncthreads();

    // per-thread candidate over its strided slice (j % 256 == t)
    float lv = -1e30f; int li = t;
    for (int j = t; j < NN; j += 256) {
        float v = sv[j];
        if (v > lv) { lv = v; li = j; }
    }

    float* ov = ws + WS_VALS + (size_t)R * KK;
    int*   oi = (int*)(ws + WS_IDX) + (size_t)R * KK;

    for (int it = 0; it < KK; ++it) {
        float v = lv; int i = li;
        #pragma unroll
        for (int m = 32; m >= 1; m >>= 1) {
            float v2 = __shfl_down(v, m);
            int   i2 = __shfl_down(i, m);
            if (v2 > v || (v2 == v && i2 < i)) { v = v2; i = i2; }
        }
        const int lane = t & 63, w = t >> 6;
        if (lane == 0) { red_v[w] = v; red_i[w] = i; }
        __syncthreads();                        // (A)
        if (t == 0) {
            float bv = red_v[0]; int bi = red_i[0];
            #pragma unroll
            for (int w2 = 1; w2 < 4; ++w2) {
                float v2 = red_v[w2]; int i2 = red_i[w2];
                if (v2 > bv || (v2 == bv && i2 < bi)) { bv = v2; bi = i2; }
            }
            win_i = bi;
            ov[it] = bv; oi[it] = bi;
        }
        __syncthreads();                        // (B)
        const int wi = win_i;
        if ((wi & 255) == t) {                  // owner removes & rescans
            sv[wi] = -1e30f;
            lv = -1e30f; li = t;
            for (int j = t; j < NN; j += 256) {
                float vv = sv[j];
                if (vv > lv) { lv = vv; li = j; }
            }
        }
        // no barrier needed: win_i rewritten only after next (A)
    }
}

// =====================================================================
// K2: Hbins[b,o] = sum_{i,k} val * kappa. 256 blocks x 32 rows each.
// Per-thread partials -> LDS tree -> 1 atomicAdd per bin per block.
// =====================================================================
__global__ __launch_bounds__(256) void k_hbins(const float* __restrict__ bins,
                                               float* __restrict__ ws) {
    __shared__ float lval[1024], ldx[1024], ldy[1024];
    __shared__ float part[8][KOb];
    const int blk = blockIdx.x;
    const int t = threadIdx.x;
    const int row0 = blk * 32;                 // 32 rows per block
    const int b = row0 / NN;

    for (int e = t; e < 1024; e += 256) {
        const int R = row0 + (e >> 5);
        const int k = e & 31;
        const int r = R - b * NN;
        const int c = ((int*)(ws + WS_IDX))[(size_t)R * KK + k];
        lval[e] = ws[WS_VALS + (size_t)R * KK + k];
        ldx[e] = (float)((c & 63) - (r & 63));
        ldy[e] = (float)((c >> 6) - (r >> 6));
    }
    __syncthreads();

    const int o = t & 31, g = t >> 5;
    const float bx = bins[2 * o], by = bins[2 * o + 1];
    float acc = 0.f;
    for (int e = g; e < 1024; e += 8) {
        const float dx = ldx[e] - bx, dy = ldy[e] - by;
        acc += lval[e] * __expf(-(dx * dx + dy * dy) * (1.0f / 4.5f));
    }
    part[g][o] = acc;
    __syncthreads();
    if (t < 32) {
        float s = 0.f;
        #pragma unroll
        for (int g2 = 0; g2 < 8; ++g2) s += part[g2][t];
        atomicAdd(ws + WS_HB + b * KOb + t, s);
    }
}

// =====================================================================
// K3: Wsoft = softmax(eta*Hbins) per batch; W_mean = mean over batches.
// 1 block, 64 threads (lane halves = batches). Max-subtracted (logits big).
// =====================================================================
__global__ void k_wsoft(float* __restrict__ ws) {
    __shared__ float sw[64];
    const int t = threadIdx.x;
    const int b = t >> 5, o = t & 31;
    const float h = 8.0f * ws[WS_HB + b * KOb + o];
    float mx = h;
    #pragma unroll
    for (int m = 16; m >= 1; m >>= 1) mx = fmaxf(mx, __shfl_xor(mx, m));
    const float e = __expf(h - mx);
    float s = e;
    #pragma unroll
    for (int m = 16; m >= 1; m >>= 1) s += __shfl_xor(s, m);
    const float w = e / s;
    ws[WS_WSOFT + b * KOb + o] = w;
    sw[t] = w;
    __syncthreads();
    if (t < 32) ws[WS_WMEAN + t] = 0.5f * (sw[t] + sw[32 + t]);
}

// =====================================================================
// K4: per-row: R_edges -> A1_edges -> entropy -> U, m; also chi.
// 1 wave per row (lanes 0..31 = edges), 4 rows per 256-thr block.
// =====================================================================
__global__ __launch_bounds__(256) void k_row1(const float* __restrict__ bins,
                                              float* __restrict__ ws,
                                              float* __restrict__ out_u) {
    const int t = threadIdx.x;
    const int wv = t >> 6, lane = t & 63;
    const int R = blockIdx.x * 4 + wv;
    const int b = R >> 12;
    const int r = R & (NN - 1);
    const bool act = lane < 32;
    const int k = lane;

    float val = 0.f, Redge = 0.f, chi = 0.f;
    if (act) {
        val = ws[WS_VALS + (size_t)R * KK + k];
        const int c = ((int*)(ws + WS_IDX))[(size_t)R * KK + k];
        const float dx0 = (float)((c & 63) - (r & 63));
        const float dy0 = (float)((c >> 6) - (r >> 6));
        float racc = 0.f, cacc = 0.f;
        for (int o = 0; o < KOb; ++o) {
            const float dx = dx0 - bins[2 * o], dy = dy0 - bins[2 * o + 1];
            const float kap = __expf(-(dx * dx + dy * dy) * (1.0f / 4.5f));
            racc += ws[WS_WSOFT + b * KOb + o] * kap;
            cacc += ws[WS_WMEAN + o] * kap;
        }
        Redge = 0.001f + racc;
        chi = cacc;
    }
    const float tilde = act ? val * Redge : 0.f;
    float s = tilde;
    #pragma unroll
    for (int m = 16; m >= 1; m >>= 1) s += __shfl_xor(s, m);  // sums within 32-lane half
    const float a1 = tilde / (s + EPS);

    // entropy of softmax(10*a1) over the 32 edges
    const float z = act ? 10.f * a1 : -1e30f;
    float mz = z;
    #pragma unroll
    for (int m = 16; m >= 1; m >>= 1) mz = fmaxf(mz, __shfl_xor(mz, m));
    const float e = act ? __expf(z - mz) : 0.f;
    float se = e;
    #pragma unroll
    for (int m = 16; m >= 1; m >>= 1) se += __shfl_xor(se, m);
    const float p = e / se;
    const float ent_t = act ? -p * __logf(p + EPS) : 0.f;
    float ent = ent_t;
    #pragma unroll
    for (int m = 16; m >= 1; m >>= 1) ent += __shfl_xor(ent, m);
    const float U = 1.f / (1.f + __expf(ent));   // sigmoid(-entropy)

    if (act) {
        ws[WS_A1  + (size_t)R * KK + k] = a1;
        ws[WS_CHI + (size_t)R * KK + k] = chi;
    }
    if (lane == 0) { out_u[R] = U; ws[WS_M + R] = 1.f - U; }
}

// =====================================================================
// K5: per-row: hatA = m_i*A1*m_j -> A2_edges -> dense-normalized values;
// scatter into dense out; also q = sum softmax(8*A2_edges)*chi.
// =====================================================================
__global__ __launch_bounds__(256) void k_row2(float* __restrict__ ws,
                                              float* __restrict__ outA2) {
    const int t = threadIdx.x;
    const int wv = t >> 6, lane = t & 63;
    const int R = blockIdx.x * 4 + wv;
    const int b = R >> 12;
    const int r = R & (NN - 1);
    const bool act = lane < 32;
    const int k = lane;

    const float mi = ws[WS_M + R];
    float a1 = 0.f; int c = 0; float mj = 0.f;
    if (act) {
        a1 = ws[WS_A1 + (size_t)R * KK + k];
        c = ((int*)(ws + WS_IDX))[(size_t)R * KK + k];
        mj = ws[WS_M + b * NN + c];
    }
    const float hat = act ? mi * a1 * mj : 0.f;
    float S = hat;
    #pragma unroll
    for (int m = 16; m >= 1; m >>= 1) S += __shfl_xor(S, m);
    const float a2e = hat / (S + EPS);          // edge-level A2_edges
    float S2 = a2e;
    #pragma unroll
    for (int m = 16; m >= 1; m >>= 1) S2 += __shfl_xor(S2, m);
    const float dv = a2e / (S2 + EPS);          // dense row-normalized value
    if (act) {
        ws[WS_A2 + (size_t)R * KK + k] = dv;
        outA2[(size_t)b * NN * NN + (size_t)r * NN + c] = dv;
    }

    // q = sum_k softmax(8*A2_edges)_k * chi_k
    const float z = act ? 8.f * a2e : -1e30f;
    float mz = z;
    #pragma unroll
    for (int m = 16; m >= 1; m >>= 1) mz = fmaxf(mz, __shfl_xor(mz, m));
    const float e = act ? __expf(z - mz) : 0.f;
    float se = e;
    #pragma unroll
    for (int m = 16; m >= 1; m >>= 1) se += __shfl_xor(se, m);
    const float wl = e / se;
    const float chi = act ? ws[WS_CHI + (size_t)R * KK + k] : 0.f;
    float q = act ? wl * chi : 0.f;
    #pragma unroll
    for (int m = 16; m >= 1; m >>= 1) q += __shfl_xor(q, m);
    if (lane == 0) ws[WS_Q + R] = q;
}

// =====================================================================
// K6: directional evidence. For each edge (r->c): P_dir from fwd/rev
// dense values (rev gathered from the dense output), s_ev reduced
// per-row, t_ev scattered atomically to target node.
// =====================================================================
__global__ __launch_bounds__(256) void k_dir(float* __restrict__ ws,
                                             const float* __restrict__ A2d) {
    const int t = threadIdx.x;
    const int wv = t >> 6, lane = t & 63;
    const int R = blockIdx.x * 4 + wv;
    const int b = R >> 12;
    const int r = R & (NN - 1);
    const bool act = lane < 32;
    const int k = lane;

    float a = 0.f; int c = r;
    if (act) {
        a = ws[WS_A2 + (size_t)R * KK + k];
        c = ((int*)(ws + WS_IDX))[(size_t)R * KK + k];
    }
    float pdir = 0.f;                           // diagonal: P_dir zeroed
    if (act && c != r) {
        const float arev = A2d[(size_t)b * NN * NN + (size_t)c * NN + r];
        const float ef = __expf(8.f * a), er = __expf(8.f * arev);
        pdir = ef / (ef + er + EPS);
    }
    float s = a * pdir;
    #pragma unroll
    for (int m = 16; m >= 1; m >>= 1) s += __shfl_xor(s, m);
    if (lane == 0) ws[WS_SEV + R] = s;
    if (act) atomicAdd(ws + WS_TEV + b * NN + c, a * (1.f - pdir));
}

// K7: pi_src / pi_tgt
__global__ void k_pi(const float* __restrict__ ws,
                     float* __restrict__ out_psrc, float* __restrict__ out_ptgt) {
    const int i = blockIdx.x * 256 + threadIdx.x;
    const float s = ws[WS_SEV + i], tv = ws[WS_TEV + i];
    const float ps = s / (s + tv + EPS);
    out_psrc[i] = ps;
    out_ptgt[i] = 1.f - ps;
}

// K8: 5x5 gaussian smoothing (correlation, zero pad) + sigmoid
__global__ void k_conv(const float* __restrict__ ws, const float* __restrict__ kern,
                       float* __restrict__ out_map) {
    const int i = blockIdx.x * 256 + threadIdx.x;   // [0, B*4096)
    const int b = i >> 12;
    const int pix = i & 4095;
    const int y = pix >> 6, x = pix & 63;
    float acc = 0.f;
    #pragma unroll
    for (int ky = 0; ky < 5; ++ky) {
        const int yy = y + ky - 2;
        if (yy < 0 || yy >= 64) continue;
        #pragma unroll
        for (int kx = 0; kx < 5; ++kx) {
            const int xx = x + kx - 2;
            if (xx < 0 || xx >= 64) continue;
            acc += ws[WS_Q + b * 4096 + yy * 64 + xx] * kern[ky * 5 + kx];
        }
    }
    out_map[i] = 1.f / (1.f + __expf(-acc));
}

extern "C" void kernel_launch(void* const* d_in, const int* in_sizes, int n_in,
                              void* d_out, int out_size, void* d_ws, size_t ws_size,
                              hipStream_t stream) {
    // setup_inputs order: E (unused), A0, P (implicit grid), bins, smooth_kernel
    const float* A0   = (const float*)d_in[1];
    const float* bins = (const float*)d_in[3];
    const float* kern = (const float*)d_in[4];
    float* out = (float*)d_out;
    float* ws  = (float*)d_ws;

    // zero dense A2 output region + the two accumulators (ws is 0xAA-poisoned)
    hipMemsetAsync(out, 0, (size_t)BB * NN * NN * sizeof(float), stream);
    hipMemsetAsync(ws + WS_HB, 0, BB * KOb * sizeof(float), stream);
    hipMemsetAsync(ws + WS_TEV, 0, BB * NN * sizeof(float), stream);

    k_topk <<<BB * NN,      256, 0, stream>>>(A0, ws);
    k_hbins<<<256,          256, 0, stream>>>(bins, ws);
    k_wsoft<<<1,             64, 0, stream>>>(ws);
    k_row1 <<<BB * NN / 4,  256, 0, stream>>>(bins, ws, out + OUT_U);
    k_row2 <<<BB * NN / 4,  256, 0, stream>>>(ws, out);
    k_dir  <<<BB * NN / 4,  256, 0, stream>>>(ws, out);
    k_pi   <<<BB * NN / 256, 256, 0, stream>>>(ws, out + OUT_PSRC, out + OUT_PTGT);
    k_conv <<<BB * NN / 256, 256, 0, stream>>>(ws, kern, out + OUT_MAP);
}

// Round 2
// 352.710 us; speedup vs baseline: 1.5573x; 1.5573x over previous
//
#include <hip/hip_runtime.h>
#include <math.h>

#define NN 4096
#define KK 32
#define KOb 32
#define BB 2

constexpr float EPS = 1e-6f;

// ---- workspace layout (in float elements) ----
#define WS_VALS   0                         // B*N*K floats
#define WS_IDX    (WS_VALS + BB*NN*KK)      // B*N*K ints
#define WS_HB     (WS_IDX + BB*NN*KK)       // B*KO
#define WS_WSOFT  (WS_HB + BB*KOb)          // B*KO
#define WS_WMEAN  (WS_WSOFT + BB*KOb)       // KO
#define WS_A1     (WS_WMEAN + KOb)          // B*N*K
#define WS_M      (WS_A1 + BB*NN*KK)        // B*N
#define WS_CHI    (WS_M + BB*NN)            // B*N*K
#define WS_A2     (WS_CHI + BB*NN*KK)       // B*N*K (dense-normalized edge vals)
#define WS_SEV    (WS_A2 + BB*NN*KK)        // B*N
#define WS_TEV    (WS_SEV + BB*NN)          // B*N  (atomic accum, zeroed in k_row2)
#define WS_Q      (WS_TEV + BB*NN)          // B*N

// ---- output layout (float elements) ----
#define OUT_A2   0
#define OUT_U    ((size_t)BB*NN*NN)
#define OUT_PSRC (OUT_U + BB*NN)
#define OUT_PTGT (OUT_PSRC + BB*NN)
#define OUT_MAP  (OUT_PTGT + BB*NN)

__device__ __forceinline__ unsigned int fkey(float x) {
    unsigned int u = __float_as_uint(x);
    return u ^ ((unsigned int)((int)u >> 31) | 0x80000000u);
}
__device__ __forceinline__ float key2f(unsigned int k) {
    unsigned int u = (k & 0x80000000u) ? (k ^ 0x80000000u) : ~k;
    return __uint_as_float(u);
}

// =====================================================================
// K1: per-row top-32. One wave per row, 64 values/lane in registers.
// Threshold search by ballot-counting (2 heuristic probes + bisection
// fallback), compact <=128 candidates to LDS as packed u64
// (key<<32 | (4095-idx)) for exact value-then-lowest-index order,
// then 32 butterfly-argmax extraction rounds. No block barriers in the
// hot path.
// =====================================================================
__global__ __launch_bounds__(256) void k_topk(const float* __restrict__ A0,
                                              float* __restrict__ ws) {
    __shared__ unsigned long long cand[4][128];

    const int t = threadIdx.x;
    const int wv = t >> 6, lane = t & 63;
    const int R = blockIdx.x * 4 + wv;

    // fold tiny zero-init of Hbins accumulator into this kernel
    if (blockIdx.x == 0 && t < BB * KOb) ws[WS_HB + t] = 0.f;

    // load 64 contiguous elements per lane (blocked layout): e = lane*64 + j
    const float4* rowv = (const float4*)(A0 + (size_t)R * NN + lane * 64);
    unsigned int key[64];
    #pragma unroll
    for (int j4 = 0; j4 < 16; ++j4) {
        const float4 f = rowv[j4];
        key[4 * j4 + 0] = fkey(f.x);
        key[4 * j4 + 1] = fkey(f.y);
        key[4 * j4 + 2] = fkey(f.z);
        key[4 * j4 + 3] = fkey(f.w);
    }

    // ---- threshold search: find lo with 32 <= count(key > lo) <= 128 ----
    unsigned int lo = 0u, hi = 0xFFFFFFFFu;
    int cnt = NN;                 // count(key > 0) for non-NaN data
    int it = 0;
    while (cnt > 128) {
        unsigned int mid;
        if (it == 0)      mid = 0xBF7E0000u;   // fkey(0.9921875f)
        else if (it == 1) mid = 0xBF7C4000u;   // fkey(0.98535f)
        else              mid = lo + ((hi - lo) >> 1);
        if (mid <= lo || mid >= hi) mid = lo + ((hi - lo) >> 1);
        if (mid == lo) break;     // range exhausted (mass ties) — cap below
        int c = 0;
        #pragma unroll
        for (int j = 0; j < 64; ++j) c += (key[j] > mid) ? 1 : 0;
        #pragma unroll
        for (int m = 32; m >= 1; m >>= 1) c += __shfl_xor(c, m);
        if (c >= KK) { lo = mid; cnt = c; } else hi = mid;
        if (++it > 48) break;
    }

    // ---- ballot-compact candidates {key > lo} into LDS ----
    int base = 0;
    #pragma unroll
    for (int j = 0; j < 64; ++j) {
        const bool p = key[j] > lo;
        const unsigned long long m = __ballot(p);
        if (p) {
            const int slot = base + __popcll(m & ((1ull << lane) - 1ull));
            if (slot < 128) {
                const unsigned int gidx = lane * 64 + j;
                cand[wv][slot] = ((unsigned long long)key[j] << 32)
                               | (unsigned long long)(4095u - gidx);
            }
        }
        base += __popcll(m);
    }
    const int ncand = (base < 128) ? base : 128;
    __syncthreads();   // every wave reaches exactly once; makes LDS writes visible

    // ---- 32 extraction rounds over 2 candidates per lane ----
    unsigned long long c0 = (lane < ncand) ? cand[wv][lane] : 0ull;
    unsigned long long c1 = (lane + 64 < ncand) ? cand[wv][lane + 64] : 0ull;
    unsigned long long resk = 0ull;
    for (int r = 0; r < KK; ++r) {
        unsigned long long bst = (c0 > c1) ? c0 : c1;
        #pragma unroll
        for (int m = 32; m >= 1; m >>= 1) {
            const unsigned long long o = __shfl_xor(bst, m);
            if (o > bst) bst = o;
        }
        if (lane == r) resk = bst;
        if (c0 == bst) c0 = 0ull;   // packed values unique (gidx unique)
        if (c1 == bst) c1 = 0ull;
    }
    if (lane < KK) {
        const unsigned int k = (unsigned int)(resk >> 32);
        const int gidx = 4095 - (int)(resk & 0xFFFull);
        ws[WS_VALS + (size_t)R * KK + lane] = key2f(k);
        ((int*)(ws + WS_IDX))[(size_t)R * KK + lane] = gidx;
    }
}

// =====================================================================
// K2: Hbins[b,o] = sum_{i,k} val * kappa. 256 blocks x 32 rows each.
// =====================================================================
__global__ __launch_bounds__(256) void k_hbins(const float* __restrict__ bins,
                                               float* __restrict__ ws) {
    __shared__ float lval[1024], ldx[1024], ldy[1024];
    __shared__ float part[8][KOb];
    const int blk = blockIdx.x;
    const int t = threadIdx.x;
    const int row0 = blk * 32;
    const int b = row0 / NN;

    for (int e = t; e < 1024; e += 256) {
        const int R = row0 + (e >> 5);
        const int k = e & 31;
        const int r = R - b * NN;
        const int c = ((int*)(ws + WS_IDX))[(size_t)R * KK + k];
        lval[e] = ws[WS_VALS + (size_t)R * KK + k];
        ldx[e] = (float)((c & 63) - (r & 63));
        ldy[e] = (float)((c >> 6) - (r >> 6));
    }
    __syncthreads();

    const int o = t & 31, g = t >> 5;
    const float bx = bins[2 * o], by = bins[2 * o + 1];
    float acc = 0.f;
    for (int e = g; e < 1024; e += 8) {
        const float dx = ldx[e] - bx, dy = ldy[e] - by;
        acc += lval[e] * __expf(-(dx * dx + dy * dy) * (1.0f / 4.5f));
    }
    part[g][o] = acc;
    __syncthreads();
    if (t < 32) {
        float s = 0.f;
        #pragma unroll
        for (int g2 = 0; g2 < 8; ++g2) s += part[g2][t];
        atomicAdd(ws + WS_HB + b * KOb + t, s);
    }
}

// =====================================================================
// K3: Wsoft = softmax(eta*Hbins) per batch; W_mean over batches.
// =====================================================================
__global__ void k_wsoft(float* __restrict__ ws) {
    __shared__ float sw[64];
    const int t = threadIdx.x;
    const int b = t >> 5, o = t & 31;
    const float h = 8.0f * ws[WS_HB + b * KOb + o];
    float mx = h;
    #pragma unroll
    for (int m = 16; m >= 1; m >>= 1) mx = fmaxf(mx, __shfl_xor(mx, m));
    const float e = __expf(h - mx);
    float s = e;
    #pragma unroll
    for (int m = 16; m >= 1; m >>= 1) s += __shfl_xor(s, m);
    const float w = e / s;
    ws[WS_WSOFT + b * KOb + o] = w;
    sw[t] = w;
    __syncthreads();
    if (t < 32) ws[WS_WMEAN + t] = 0.5f * (sw[t] + sw[32 + t]);
}

// =====================================================================
// K4: per-row: R_edges -> A1 -> entropy -> U, m; also chi.
// =====================================================================
__global__ __launch_bounds__(256) void k_row1(const float* __restrict__ bins,
                                              float* __restrict__ ws,
                                              float* __restrict__ out_u) {
    __shared__ float sbins[2 * KOb], swsoft[BB * KOb], swmean[KOb];
    const int t = threadIdx.x;
    if (t < 2 * KOb) sbins[t] = bins[t];
    if (t >= 64 && t < 64 + BB * KOb) swsoft[t - 64] = ws[WS_WSOFT + t - 64];
    if (t >= 128 && t < 128 + KOb) swmean[t - 128] = ws[WS_WMEAN + t - 128];
    __syncthreads();

    const int wv = t >> 6, lane = t & 63;
    const int R = blockIdx.x * 4 + wv;
    const int b = R >> 12;
    const int r = R & (NN - 1);
    const bool act = lane < 32;
    const int k = lane;

    float val = 0.f, Redge = 0.f, chi = 0.f;
    if (act) {
        val = ws[WS_VALS + (size_t)R * KK + k];
        const int c = ((int*)(ws + WS_IDX))[(size_t)R * KK + k];
        const float dx0 = (float)((c & 63) - (r & 63));
        const float dy0 = (float)((c >> 6) - (r >> 6));
        float racc = 0.f, cacc = 0.f;
        for (int o = 0; o < KOb; ++o) {
            const float dx = dx0 - sbins[2 * o], dy = dy0 - sbins[2 * o + 1];
            const float kap = __expf(-(dx * dx + dy * dy) * (1.0f / 4.5f));
            racc += swsoft[b * KOb + o] * kap;
            cacc += swmean[o] * kap;
        }
        Redge = 0.001f + racc;
        chi = cacc;
    }
    const float tilde = act ? val * Redge : 0.f;
    float s = tilde;
    #pragma unroll
    for (int m = 16; m >= 1; m >>= 1) s += __shfl_xor(s, m);
    const float a1 = tilde / (s + EPS);

    const float z = act ? 10.f * a1 : -1e30f;
    float mz = z;
    #pragma unroll
    for (int m = 16; m >= 1; m >>= 1) mz = fmaxf(mz, __shfl_xor(mz, m));
    const float e = act ? __expf(z - mz) : 0.f;
    float se = e;
    #pragma unroll
    for (int m = 16; m >= 1; m >>= 1) se += __shfl_xor(se, m);
    const float p = e / se;
    const float ent_t = act ? -p * __logf(p + EPS) : 0.f;
    float ent = ent_t;
    #pragma unroll
    for (int m = 16; m >= 1; m >>= 1) ent += __shfl_xor(ent, m);
    const float U = 1.f / (1.f + __expf(ent));

    if (act) {
        ws[WS_A1  + (size_t)R * KK + k] = a1;
        ws[WS_CHI + (size_t)R * KK + k] = chi;
    }
    if (lane == 0) { out_u[R] = U; ws[WS_M + R] = 1.f - U; }
}

// =====================================================================
// K5: per-row: hatA -> A2_edges -> dense-normalized vals (to ws only);
// q = sum softmax(8*A2_edges)*chi. Also zero-fills WS_TEV for K_dir.
// =====================================================================
__global__ __launch_bounds__(256) void k_row2(float* __restrict__ ws) {
    const int gid = blockIdx.x * 256 + threadIdx.x;
    if (gid < BB * NN) ws[WS_TEV + gid] = 0.f;

    const int t = threadIdx.x;
    const int wv = t >> 6, lane = t & 63;
    const int R = blockIdx.x * 4 + wv;
    const int b = R >> 12;
    const bool act = lane < 32;
    const int k = lane;

    const float mi = ws[WS_M + R];
    float a1 = 0.f; int c = 0; float mj = 0.f;
    if (act) {
        a1 = ws[WS_A1 + (size_t)R * KK + k];
        c = ((int*)(ws + WS_IDX))[(size_t)R * KK + k];
        mj = ws[WS_M + b * NN + c];
    }
    const float hat = act ? mi * a1 * mj : 0.f;
    float S = hat;
    #pragma unroll
    for (int m = 16; m >= 1; m >>= 1) S += __shfl_xor(S, m);
    const float a2e = hat / (S + EPS);
    float S2 = a2e;
    #pragma unroll
    for (int m = 16; m >= 1; m >>= 1) S2 += __shfl_xor(S2, m);
    const float dv = a2e / (S2 + EPS);
    if (act) ws[WS_A2 + (size_t)R * KK + k] = dv;

    const float z = act ? 8.f * a2e : -1e30f;
    float mz = z;
    #pragma unroll
    for (int m = 16; m >= 1; m >>= 1) mz = fmaxf(mz, __shfl_xor(mz, m));
    const float e = act ? __expf(z - mz) : 0.f;
    float se = e;
    #pragma unroll
    for (int m = 16; m >= 1; m >>= 1) se += __shfl_xor(se, m);
    const float wl = e / se;
    const float chi = act ? ws[WS_CHI + (size_t)R * KK + k] : 0.f;
    float q = act ? wl * chi : 0.f;
    #pragma unroll
    for (int m = 16; m >= 1; m >>= 1) q += __shfl_xor(q, m);
    if (lane == 0) ws[WS_Q + R] = q;
}

// =====================================================================
// K6: write dense A2 output (replaces 134MB memset + scatter):
// stage one row in LDS, scatter 32 values, stream out coalesced.
// =====================================================================
__global__ __launch_bounds__(256) void k_dense(const float* __restrict__ ws,
                                               float* __restrict__ outA2) {
    __shared__ float srow[NN];
    __shared__ int   sidx[KK];
    __shared__ float sval[KK];
    const int R = blockIdx.x;
    const int b = R >> 12;
    const int r = R & (NN - 1);
    const int t = threadIdx.x;

    if (t < KK) {
        sidx[t] = ((const int*)(ws + WS_IDX))[(size_t)R * KK + t];
        sval[t] = ws[WS_A2 + (size_t)R * KK + t];
    }
    float4* s4 = (float4*)srow;
    const float4 z4 = make_float4(0.f, 0.f, 0.f, 0.f);
    #pragma unroll
    for (int i = 0; i < 4; ++i) s4[t + 256 * i] = z4;
    __syncthreads();
    if (t < KK) srow[sidx[t]] = sval[t];
    __syncthreads();
    float4* o4 = (float4*)(outA2 + (size_t)b * NN * NN + (size_t)r * NN);
    #pragma unroll
    for (int i = 0; i < 4; ++i) o4[t + 256 * i] = s4[t + 256 * i];
}

// =====================================================================
// K7: directional evidence (rev values gathered from dense output).
// =====================================================================
__global__ __launch_bounds__(256) void k_dir(float* __restrict__ ws,
                                             const float* __restrict__ A2d) {
    const int t = threadIdx.x;
    const int wv = t >> 6, lane = t & 63;
    const int R = blockIdx.x * 4 + wv;
    const int b = R >> 12;
    const int r = R & (NN - 1);
    const bool act = lane < 32;
    const int k = lane;

    float a = 0.f; int c = r;
    if (act) {
        a = ws[WS_A2 + (size_t)R * KK + k];
        c = ((int*)(ws + WS_IDX))[(size_t)R * KK + k];
    }
    float pdir = 0.f;
    if (act && c != r) {
        const float arev = A2d[(size_t)b * NN * NN + (size_t)c * NN + r];
        const float ef = __expf(8.f * a), er = __expf(8.f * arev);
        pdir = ef / (ef + er + EPS);
    }
    float s = a * pdir;
    #pragma unroll
    for (int m = 16; m >= 1; m >>= 1) s += __shfl_xor(s, m);
    if (lane == 0) ws[WS_SEV + R] = s;
    if (act) atomicAdd(ws + WS_TEV + b * NN + c, a * (1.f - pdir));
}

// =====================================================================
// K8: fused pi_src/pi_tgt + 5x5 gaussian smoothing + sigmoid.
// =====================================================================
__global__ void k_tail(const float* __restrict__ ws, const float* __restrict__ kern,
                       float* __restrict__ out_psrc, float* __restrict__ out_ptgt,
                       float* __restrict__ out_map) {
    const int i = blockIdx.x * 256 + threadIdx.x;   // [0, B*4096)
    const float s = ws[WS_SEV + i], tv = ws[WS_TEV + i];
    const float ps = s / (s + tv + EPS);
    out_psrc[i] = ps;
    out_ptgt[i] = 1.f - ps;

    const int b = i >> 12;
    const int pix = i & 4095;
    const int y = pix >> 6, x = pix & 63;
    float acc = 0.f;
    #pragma unroll
    for (int ky = 0; ky < 5; ++ky) {
        const int yy = y + ky - 2;
        if (yy < 0 || yy >= 64) continue;
        #pragma unroll
        for (int kx = 0; kx < 5; ++kx) {
            const int xx = x + kx - 2;
            if (xx < 0 || xx >= 64) continue;
            acc += ws[WS_Q + b * 4096 + yy * 64 + xx] * kern[ky * 5 + kx];
        }
    }
    out_map[i] = 1.f / (1.f + __expf(-acc));
}

extern "C" void kernel_launch(void* const* d_in, const int* in_sizes, int n_in,
                              void* d_out, int out_size, void* d_ws, size_t ws_size,
                              hipStream_t stream) {
    // setup_inputs order: E (unused), A0, P (implicit grid), bins, smooth_kernel
    const float* A0   = (const float*)d_in[1];
    const float* bins = (const float*)d_in[3];
    const float* kern = (const float*)d_in[4];
    float* out = (float*)d_out;
    float* ws  = (float*)d_ws;

    k_topk <<<BB * NN / 4,   256, 0, stream>>>(A0, ws);
    k_hbins<<<256,           256, 0, stream>>>(bins, ws);
    k_wsoft<<<1,              64, 0, stream>>>(ws);
    k_row1 <<<BB * NN / 4,   256, 0, stream>>>(bins, ws, out + OUT_U);
    k_row2 <<<BB * NN / 4,   256, 0, stream>>>(ws);
    k_dense<<<BB * NN,       256, 0, stream>>>(ws, out);
    k_dir  <<<BB * NN / 4,   256, 0, stream>>>(ws, out);
    k_tail <<<BB * NN / 256, 256, 0, stream>>>(ws, kern,
                                               out + OUT_PSRC, out + OUT_PTGT,
                                               out + OUT_MAP);
}

// Round 3
// 341.594 us; speedup vs baseline: 1.6080x; 1.0325x over previous
//
#include <hip/hip_runtime.h>
#include <math.h>

#define NN 4096
#define KK 32
#define KOb 32
#define BB 2

constexpr float EPS = 1e-6f;

// ---- workspace layout (in float elements) ----
#define WS_VALS   0                         // B*N*K floats
#define WS_IDX    (WS_VALS + BB*NN*KK)      // B*N*K ints
#define WS_HB     (WS_IDX + BB*NN*KK)       // B*KO
#define WS_WSOFT  (WS_HB + BB*KOb)          // B*KO
#define WS_WMEAN  (WS_WSOFT + BB*KOb)       // KO
#define WS_A1     (WS_WMEAN + KOb)          // B*N*K
#define WS_M      (WS_A1 + BB*NN*KK)        // B*N
#define WS_CHI    (WS_M + BB*NN)            // B*N*K
#define WS_A2     (WS_CHI + BB*NN*KK)       // B*N*K (dense-normalized edge vals)
#define WS_SEV    (WS_A2 + BB*NN*KK)        // B*N
#define WS_TEV    (WS_SEV + BB*NN)          // B*N  (atomic accum, zeroed in k_row2)
#define WS_Q      (WS_TEV + BB*NN)          // B*N

// ---- output layout (float elements) ----
#define OUT_A2   0
#define OUT_U    ((size_t)BB*NN*NN)
#define OUT_PSRC (OUT_U + BB*NN)
#define OUT_PTGT (OUT_PSRC + BB*NN)
#define OUT_MAP  (OUT_PTGT + BB*NN)

__device__ __forceinline__ unsigned int fkey(float x) {
    unsigned int u = __float_as_uint(x);
    return u ^ ((unsigned int)((int)u >> 31) | 0x80000000u);
}
__device__ __forceinline__ float key2f(unsigned int k) {
    unsigned int u = (k & 0x80000000u) ? (k ^ 0x80000000u) : ~k;
    return __uint_as_float(u);
}

// =====================================================================
// K1: per-row top-32. One wave per row, 64 values/lane in registers,
// loaded COALESCED: lane l takes float4 at element (j4*64+l), so each
// global_load_dwordx4 is one contiguous 1KB wave transaction.
// Threshold search by ballot-counting (2 heuristic probes + bisection
// fallback), compact <=128 candidates to LDS as packed u64
// (key<<32 | (4095-idx)) for exact value-then-lowest-index order,
// then 32 butterfly-argmax extraction rounds.
// =====================================================================
__global__ __launch_bounds__(256) void k_topk(const float* __restrict__ A0,
                                              float* __restrict__ ws) {
    __shared__ unsigned long long cand[4][128];

    const int t = threadIdx.x;
    const int wv = t >> 6, lane = t & 63;
    const int R = blockIdx.x * 4 + wv;

    // fold tiny zero-init of Hbins accumulator into this kernel
    if (blockIdx.x == 0 && t < BB * KOb) ws[WS_HB + t] = 0.f;

    // coalesced: lane l reads float4 #(j4*64 + l); element index of
    // key[4*j4+c] is j4*256 + lane*4 + c
    const float4* row4 = (const float4*)(A0 + (size_t)R * NN);
    unsigned int key[64];
    #pragma unroll
    for (int j4 = 0; j4 < 16; ++j4) {
        const float4 f = row4[j4 * 64 + lane];
        key[4 * j4 + 0] = fkey(f.x);
        key[4 * j4 + 1] = fkey(f.y);
        key[4 * j4 + 2] = fkey(f.z);
        key[4 * j4 + 3] = fkey(f.w);
    }

    // ---- threshold search: find lo with 32 <= count(key > lo) <= 128 ----
    unsigned int lo = 0u, hi = 0xFFFFFFFFu;
    int cnt = NN;                 // count(key > 0) for non-NaN data
    int it = 0;
    while (cnt > 128) {
        unsigned int mid;
        if (it == 0)      mid = 0xBF7E0000u;   // fkey(0.9921875f)
        else if (it == 1) mid = 0xBF7C4000u;   // fkey(0.98535f)
        else              mid = lo + ((hi - lo) >> 1);
        if (mid <= lo || mid >= hi) mid = lo + ((hi - lo) >> 1);
        if (mid == lo) break;     // range exhausted (mass ties) — cap below
        int c = 0;
        #pragma unroll
        for (int j = 0; j < 64; ++j) c += (key[j] > mid) ? 1 : 0;
        #pragma unroll
        for (int m = 32; m >= 1; m >>= 1) c += __shfl_xor(c, m);
        if (c >= KK) { lo = mid; cnt = c; } else hi = mid;
        if (++it > 48) break;
    }

    // ---- ballot-compact candidates {key > lo} into LDS ----
    int base = 0;
    #pragma unroll
    for (int j = 0; j < 64; ++j) {
        const bool p = key[j] > lo;
        const unsigned long long m = __ballot(p);
        if (p) {
            const int slot = base + __popcll(m & ((1ull << lane) - 1ull));
            if (slot < 128) {
                const unsigned int gidx = (unsigned int)((j >> 2) * 256 + lane * 4 + (j & 3));
                cand[wv][slot] = ((unsigned long long)key[j] << 32)
                               | (unsigned long long)(4095u - gidx);
            }
        }
        base += __popcll(m);
    }
    const int ncand = (base < 128) ? base : 128;
    __syncthreads();   // every wave reaches exactly once; makes LDS writes visible

    // ---- 32 extraction rounds over 2 candidates per lane ----
    unsigned long long c0 = (lane < ncand) ? cand[wv][lane] : 0ull;
    unsigned long long c1 = (lane + 64 < ncand) ? cand[wv][lane + 64] : 0ull;
    unsigned long long resk = 0ull;
    for (int r = 0; r < KK; ++r) {
        unsigned long long bst = (c0 > c1) ? c0 : c1;
        #pragma unroll
        for (int m = 32; m >= 1; m >>= 1) {
            const unsigned long long o = __shfl_xor(bst, m);
            if (o > bst) bst = o;
        }
        if (lane == r) resk = bst;
        if (c0 == bst) c0 = 0ull;   // packed values unique (gidx unique)
        if (c1 == bst) c1 = 0ull;
    }
    if (lane < KK) {
        const unsigned int k = (unsigned int)(resk >> 32);
        const int gidx = 4095 - (int)(resk & 0xFFFull);
        ws[WS_VALS + (size_t)R * KK + lane] = key2f(k);
        ((int*)(ws + WS_IDX))[(size_t)R * KK + lane] = gidx;
    }
}

// =====================================================================
// K2: Hbins[b,o] = sum_{i,k} val * kappa. 256 blocks x 32 rows each.
// =====================================================================
__global__ __launch_bounds__(256) void k_hbins(const float* __restrict__ bins,
                                               float* __restrict__ ws) {
    __shared__ float lval[1024], ldx[1024], ldy[1024];
    __shared__ float part[8][KOb];
    const int blk = blockIdx.x;
    const int t = threadIdx.x;
    const int row0 = blk * 32;
    const int b = row0 / NN;

    for (int e = t; e < 1024; e += 256) {
        const int R = row0 + (e >> 5);
        const int k = e & 31;
        const int r = R - b * NN;
        const int c = ((int*)(ws + WS_IDX))[(size_t)R * KK + k];
        lval[e] = ws[WS_VALS + (size_t)R * KK + k];
        ldx[e] = (float)((c & 63) - (r & 63));
        ldy[e] = (float)((c >> 6) - (r >> 6));
    }
    __syncthreads();

    const int o = t & 31, g = t >> 5;
    const float bx = bins[2 * o], by = bins[2 * o + 1];
    float acc = 0.f;
    for (int e = g; e < 1024; e += 8) {
        const float dx = ldx[e] - bx, dy = ldy[e] - by;
        acc += lval[e] * __expf(-(dx * dx + dy * dy) * (1.0f / 4.5f));
    }
    part[g][o] = acc;
    __syncthreads();
    if (t < 32) {
        float s = 0.f;
        #pragma unroll
        for (int g2 = 0; g2 < 8; ++g2) s += part[g2][t];
        atomicAdd(ws + WS_HB + b * KOb + t, s);
    }
}

// =====================================================================
// K3: Wsoft = softmax(eta*Hbins) per batch; W_mean over batches.
// =====================================================================
__global__ void k_wsoft(float* __restrict__ ws) {
    __shared__ float sw[64];
    const int t = threadIdx.x;
    const int b = t >> 5, o = t & 31;
    const float h = 8.0f * ws[WS_HB + b * KOb + o];
    float mx = h;
    #pragma unroll
    for (int m = 16; m >= 1; m >>= 1) mx = fmaxf(mx, __shfl_xor(mx, m));
    const float e = __expf(h - mx);
    float s = e;
    #pragma unroll
    for (int m = 16; m >= 1; m >>= 1) s += __shfl_xor(s, m);
    const float w = e / s;
    ws[WS_WSOFT + b * KOb + o] = w;
    sw[t] = w;
    __syncthreads();
    if (t < 32) ws[WS_WMEAN + t] = 0.5f * (sw[t] + sw[32 + t]);
}

// =====================================================================
// K4: per-row: R_edges -> A1 -> entropy -> U, m; also chi.
// =====================================================================
__global__ __launch_bounds__(256) void k_row1(const float* __restrict__ bins,
                                              float* __restrict__ ws,
                                              float* __restrict__ out_u) {
    __shared__ float sbins[2 * KOb], swsoft[BB * KOb], swmean[KOb];
    const int t = threadIdx.x;
    if (t < 2 * KOb) sbins[t] = bins[t];
    if (t >= 64 && t < 64 + BB * KOb) swsoft[t - 64] = ws[WS_WSOFT + t - 64];
    if (t >= 128 && t < 128 + KOb) swmean[t - 128] = ws[WS_WMEAN + t - 128];
    __syncthreads();

    const int wv = t >> 6, lane = t & 63;
    const int R = blockIdx.x * 4 + wv;
    const int b = R >> 12;
    const int r = R & (NN - 1);
    const bool act = lane < 32;
    const int k = lane;

    float val = 0.f, Redge = 0.f, chi = 0.f;
    if (act) {
        val = ws[WS_VALS + (size_t)R * KK + k];
        const int c = ((int*)(ws + WS_IDX))[(size_t)R * KK + k];
        const float dx0 = (float)((c & 63) - (r & 63));
        const float dy0 = (float)((c >> 6) - (r >> 6));
        float racc = 0.f, cacc = 0.f;
        for (int o = 0; o < KOb; ++o) {
            const float dx = dx0 - sbins[2 * o], dy = dy0 - sbins[2 * o + 1];
            const float kap = __expf(-(dx * dx + dy * dy) * (1.0f / 4.5f));
            racc += swsoft[b * KOb + o] * kap;
            cacc += swmean[o] * kap;
        }
        Redge = 0.001f + racc;
        chi = cacc;
    }
    const float tilde = act ? val * Redge : 0.f;
    float s = tilde;
    #pragma unroll
    for (int m = 16; m >= 1; m >>= 1) s += __shfl_xor(s, m);
    const float a1 = tilde / (s + EPS);

    const float z = act ? 10.f * a1 : -1e30f;
    float mz = z;
    #pragma unroll
    for (int m = 16; m >= 1; m >>= 1) mz = fmaxf(mz, __shfl_xor(mz, m));
    const float e = act ? __expf(z - mz) : 0.f;
    float se = e;
    #pragma unroll
    for (int m = 16; m >= 1; m >>= 1) se += __shfl_xor(se, m);
    const float p = e / se;
    const float ent_t = act ? -p * __logf(p + EPS) : 0.f;
    float ent = ent_t;
    #pragma unroll
    for (int m = 16; m >= 1; m >>= 1) ent += __shfl_xor(ent, m);
    const float U = 1.f / (1.f + __expf(ent));

    if (act) {
        ws[WS_A1  + (size_t)R * KK + k] = a1;
        ws[WS_CHI + (size_t)R * KK + k] = chi;
    }
    if (lane == 0) { out_u[R] = U; ws[WS_M + R] = 1.f - U; }
}

// =====================================================================
// K5: per-row: hatA -> A2_edges -> dense-normalized vals (to ws only);
// q = sum softmax(8*A2_edges)*chi. Also zero-fills WS_TEV for k_dir.
// =====================================================================
__global__ __launch_bounds__(256) void k_row2(float* __restrict__ ws) {
    const int gid = blockIdx.x * 256 + threadIdx.x;
    if (gid < BB * NN) ws[WS_TEV + gid] = 0.f;

    const int t = threadIdx.x;
    const int wv = t >> 6, lane = t & 63;
    const int R = blockIdx.x * 4 + wv;
    const int b = R >> 12;
    const bool act = lane < 32;
    const int k = lane;

    const float mi = ws[WS_M + R];
    float a1 = 0.f; int c = 0; float mj = 0.f;
    if (act) {
        a1 = ws[WS_A1 + (size_t)R * KK + k];
        c = ((int*)(ws + WS_IDX))[(size_t)R * KK + k];
        mj = ws[WS_M + b * NN + c];
    }
    const float hat = act ? mi * a1 * mj : 0.f;
    float S = hat;
    #pragma unroll
    for (int m = 16; m >= 1; m >>= 1) S += __shfl_xor(S, m);
    const float a2e = hat / (S + EPS);
    float S2 = a2e;
    #pragma unroll
    for (int m = 16; m >= 1; m >>= 1) S2 += __shfl_xor(S2, m);
    const float dv = a2e / (S2 + EPS);
    if (act) ws[WS_A2 + (size_t)R * KK + k] = dv;

    const float z = act ? 8.f * a2e : -1e30f;
    float mz = z;
    #pragma unroll
    for (int m = 16; m >= 1; m >>= 1) mz = fmaxf(mz, __shfl_xor(mz, m));
    const float e = act ? __expf(z - mz) : 0.f;
    float se = e;
    #pragma unroll
    for (int m = 16; m >= 1; m >>= 1) se += __shfl_xor(se, m);
    const float wl = e / se;
    const float chi = act ? ws[WS_CHI + (size_t)R * KK + k] : 0.f;
    float q = act ? wl * chi : 0.f;
    #pragma unroll
    for (int m = 16; m >= 1; m >>= 1) q += __shfl_xor(q, m);
    if (lane == 0) ws[WS_Q + R] = q;
}

// =====================================================================
// K6: write dense A2 output (memset + scatter fused):
// stage one row in LDS, scatter 32 values, stream out coalesced.
// =====================================================================
__global__ __launch_bounds__(256) void k_dense(const float* __restrict__ ws,
                                               float* __restrict__ outA2) {
    __shared__ float srow[NN];
    __shared__ int   sidx[KK];
    __shared__ float sval[KK];
    const int R = blockIdx.x;
    const int b = R >> 12;
    const int r = R & (NN - 1);
    const int t = threadIdx.x;

    if (t < KK) {
        sidx[t] = ((const int*)(ws + WS_IDX))[(size_t)R * KK + t];
        sval[t] = ws[WS_A2 + (size_t)R * KK + t];
    }
    float4* s4 = (float4*)srow;
    const float4 z4 = make_float4(0.f, 0.f, 0.f, 0.f);
    #pragma unroll
    for (int i = 0; i < 4; ++i) s4[t + 256 * i] = z4;
    __syncthreads();
    if (t < KK) srow[sidx[t]] = sval[t];
    __syncthreads();
    float4* o4 = (float4*)(outA2 + (size_t)b * NN * NN + (size_t)r * NN);
    #pragma unroll
    for (int i = 0; i < 4; ++i) o4[t + 256 * i] = s4[t + 256 * i];
}

// =====================================================================
// K7: directional evidence (rev values gathered from dense output).
// =====================================================================
__global__ __launch_bounds__(256) void k_dir(float* __restrict__ ws,
                                             const float* __restrict__ A2d) {
    const int t = threadIdx.x;
    const int wv = t >> 6, lane = t & 63;
    const int R = blockIdx.x * 4 + wv;
    const int b = R >> 12;
    const int r = R & (NN - 1);
    const bool act = lane < 32;
    const int k = lane;

    float a = 0.f; int c = r;
    if (act) {
        a = ws[WS_A2 + (size_t)R * KK + k];
        c = ((int*)(ws + WS_IDX))[(size_t)R * KK + k];
    }
    float pdir = 0.f;
    if (act && c != r) {
        const float arev = A2d[(size_t)b * NN * NN + (size_t)c * NN + r];
        const float ef = __expf(8.f * a), er = __expf(8.f * arev);
        pdir = ef / (ef + er + EPS);
    }
    float s = a * pdir;
    #pragma unroll
    for (int m = 16; m >= 1; m >>= 1) s += __shfl_xor(s, m);
    if (lane == 0) ws[WS_SEV + R] = s;
    if (act) atomicAdd(ws + WS_TEV + b * NN + c, a * (1.f - pdir));
}

// =====================================================================
// K8: fused pi_src/pi_tgt + 5x5 gaussian smoothing + sigmoid.
// =====================================================================
__global__ void k_tail(const float* __restrict__ ws, const float* __restrict__ kern,
                       float* __restrict__ out_psrc, float* __restrict__ out_ptgt,
                       float* __restrict__ out_map) {
    const int i = blockIdx.x * 256 + threadIdx.x;   // [0, B*4096)
    const float s = ws[WS_SEV + i], tv = ws[WS_TEV + i];
    const float ps = s / (s + tv + EPS);
    out_psrc[i] = ps;
    out_ptgt[i] = 1.f - ps;

    const int b = i >> 12;
    const int pix = i & 4095;
    const int y = pix >> 6, x = pix & 63;
    float acc = 0.f;
    #pragma unroll
    for (int ky = 0; ky < 5; ++ky) {
        const int yy = y + ky - 2;
        if (yy < 0 || yy >= 64) continue;
        #pragma unroll
        for (int kx = 0; kx < 5; ++kx) {
            const int xx = x + kx - 2;
            if (xx < 0 || xx >= 64) continue;
            acc += ws[WS_Q + b * 4096 + yy * 64 + xx] * kern[ky * 5 + kx];
        }
    }
    out_map[i] = 1.f / (1.f + __expf(-acc));
}

extern "C" void kernel_launch(void* const* d_in, const int* in_sizes, int n_in,
                              void* d_out, int out_size, void* d_ws, size_t ws_size,
                              hipStream_t stream) {
    // setup_inputs order: E (unused), A0, P (implicit grid), bins, smooth_kernel
    const float* A0   = (const float*)d_in[1];
    const float* bins = (const float*)d_in[3];
    const float* kern = (const float*)d_in[4];
    float* out = (float*)d_out;
    float* ws  = (float*)d_ws;

    k_topk <<<BB * NN / 4,   256, 0, stream>>>(A0, ws);
    k_hbins<<<256,           256, 0, stream>>>(bins, ws);
    k_wsoft<<<1,              64, 0, stream>>>(ws);
    k_row1 <<<BB * NN / 4,   256, 0, stream>>>(bins, ws, out + OUT_U);
    k_row2 <<<BB * NN / 4,   256, 0, stream>>>(ws);
    k_dense<<<BB * NN,       256, 0, stream>>>(ws, out);
    k_dir  <<<BB * NN / 4,   256, 0, stream>>>(ws, out);
    k_tail <<<BB * NN / 256, 256, 0, stream>>>(ws, kern,
                                               out + OUT_PSRC, out + OUT_PTGT,
                                               out + OUT_MAP);
}

// Round 4
// 333.937 us; speedup vs baseline: 1.6448x; 1.0229x over previous
//
#include <hip/hip_runtime.h>
#include <math.h>

#define NN 4096
#define KK 32
#define KOb 32
#define BB 2
#define NSLOT 64   // Hbins partial slots (bounds global atomic contention)

constexpr float EPS = 1e-6f;

// ---- workspace layout (in float elements) ----
#define WS_VALS   0                          // B*N*K floats
#define WS_IDX    (WS_VALS + BB*NN*KK)       // B*N*K ints
#define WS_HBP    (WS_IDX + BB*NN*KK)        // B*NSLOT*KO partials (memset 0)
#define WS_A1     (WS_HBP + BB*NSLOT*KOb)    // B*N*K
#define WS_M      (WS_A1 + BB*NN*KK)         // B*N
#define WS_CHI    (WS_M + BB*NN)             // B*N*K
#define WS_A2     (WS_CHI + BB*NN*KK)        // B*N*K
#define WS_SEV    (WS_A2 + BB*NN*KK)         // B*N
#define WS_TEV    (WS_SEV + BB*NN)           // B*N (zeroed in k_row2d)
#define WS_Q      (WS_TEV + BB*NN)           // B*N

// ---- output layout (float elements) ----
#define OUT_A2   0
#define OUT_U    ((size_t)BB*NN*NN)
#define OUT_PSRC (OUT_U + BB*NN)
#define OUT_PTGT (OUT_PSRC + BB*NN)
#define OUT_MAP  (OUT_PTGT + BB*NN)

__device__ __forceinline__ unsigned int fkey(float x) {
    unsigned int u = __float_as_uint(x);
    return u ^ ((unsigned int)((int)u >> 31) | 0x80000000u);
}
__device__ __forceinline__ float key2f(unsigned int k) {
    unsigned int u = (k & 0x80000000u) ? (k ^ 0x80000000u) : ~k;
    return __uint_as_float(u);
}

// =====================================================================
// K1: per-row top-32 via rank selection (no serial extraction chain)
// + fused Hbins partial accumulation.
// One wave per row; 64 keys/lane in registers, coalesced float4 loads.
// Threshold search to 32<=cnt<=64, compact to 1 candidate/lane in LDS,
// rank via 64 readlane broadcasts (independent ops), scatter by rank.
// =====================================================================
__global__ __launch_bounds__(256) void k_topk(const float* __restrict__ A0,
                                              const float* __restrict__ bins,
                                              float* __restrict__ ws) {
    __shared__ unsigned long long cand[4][64];
    __shared__ float sbins[2 * KOb];
    __shared__ float shb[KOb];

    const int t = threadIdx.x;
    const int wv = t >> 6, lane = t & 63;
    const int R = blockIdx.x * 4 + wv;
    const int b = blockIdx.x >> 10;            // rows in a block share batch
    const int r = R & (NN - 1);

    if (t < 2 * KOb) sbins[t] = bins[t];
    if (t < KOb) shb[t] = 0.f;

    // coalesced: lane l reads float4 #(j4*64+l); elem of key[4*j4+c] = j4*256+l*4+c
    const float4* row4 = (const float4*)(A0 + (size_t)R * NN);
    unsigned int key[64];
    #pragma unroll
    for (int j4 = 0; j4 < 16; ++j4) {
        const float4 f = row4[j4 * 64 + lane];
        key[4 * j4 + 0] = fkey(f.x);
        key[4 * j4 + 1] = fkey(f.y);
        key[4 * j4 + 2] = fkey(f.z);
        key[4 * j4 + 3] = fkey(f.w);
    }

    // ---- threshold: find lo with 32 <= count(key > lo) <= 64 ----
    unsigned int lo = 0u, hi = 0xFFFFFFFFu;
    int cnt = NN, myc = 64, it = 0;
    while (cnt > 64) {
        unsigned int mid;
        if (it == 0)      mid = 0xBF7E0000u;   // fkey(0.9921875) ~ E[cnt]=32
        else if (it == 1) mid = 0xBF7C4000u;   // fkey(0.98535)  ~ E[cnt]=60
        else              mid = lo + ((hi - lo) >> 1);
        if (mid <= lo || mid >= hi) mid = lo + ((hi - lo) >> 1);
        if (mid == lo) break;
        int cl = 0;
        #pragma unroll
        for (int j = 0; j < 64; ++j) cl += (key[j] > mid) ? 1 : 0;
        int c = cl;
        #pragma unroll
        for (int m = 32; m >= 1; m >>= 1) c += __shfl_xor(c, m);
        if (c >= KK) { lo = mid; cnt = c; myc = cl; } else hi = mid;
        if (++it > 48) break;
    }
    if (lo == 0u) {   // degenerate: recompute per-lane count at lo=0
        int cl = 0;
        #pragma unroll
        for (int j = 0; j < 64; ++j) cl += (key[j] > 0u) ? 1 : 0;
        myc = cl;
    }

    // ---- exclusive prefix of per-lane candidate counts ----
    int pre = myc;
    #pragma unroll
    for (int m = 1; m < 64; m <<= 1) {
        const int o = __shfl_up(pre, m);
        if (lane >= m) pre += o;
    }
    pre -= myc;

    // ---- compact candidates (one per LDS slot), packed for tie-break ----
    int slot = pre;
    #pragma unroll
    for (int j = 0; j < 64; ++j) {
        if (key[j] > lo && slot < 64) {
            const unsigned int gidx = (unsigned int)((j >> 2) * 256 + lane * 4 + (j & 3));
            cand[wv][slot] = ((unsigned long long)key[j] << 32)
                           | (unsigned long long)(4095u - gidx);
            ++slot;
        }
    }
    const int ncand = (cnt < 64) ? cnt : 64;
    __syncthreads();    // all waves hit once; also covers sbins/shb init

    // ---- rank selection: rank = #candidates greater than mine ----
    const unsigned long long cd = (lane < ncand) ? cand[wv][lane] : 0ull;
    int rank = 0;
    #pragma unroll
    for (int i = 0; i < 64; ++i) {
        const unsigned long long o = __shfl(cd, i);   // readlane broadcast
        rank += (o > cd) ? 1 : 0;
    }

    const bool sel = (lane < ncand) && (rank < KK);
    float val = 0.f; int gidx = 0;
    if (sel) {
        val = key2f((unsigned int)(cd >> 32));
        gidx = 4095 - (int)(cd & 0xFFFull);
        ws[WS_VALS + (size_t)R * KK + rank] = val;
        ((int*)(ws + WS_IDX))[(size_t)R * KK + rank] = gidx;
    }

    // ---- fused Hbins: selected lanes accumulate val*kappa per bin ----
    if (sel) {
        const float dx0 = (float)((gidx & 63) - (r & 63));
        const float dy0 = (float)((gidx >> 6) - (r >> 6));
        #pragma unroll
        for (int oo = 0; oo < KOb; ++oo) {
            const int o = (oo + lane) & 31;            // stagger banks
            const float dx = dx0 - sbins[2 * o], dy = dy0 - sbins[2 * o + 1];
            atomicAdd(&shb[o], val * __expf(-(dx * dx + dy * dy) * (1.0f / 4.5f)));
        }
    }
    __syncthreads();
    if (t < KOb)
        atomicAdd(ws + WS_HBP + b * (NSLOT * KOb) + (blockIdx.x & (NSLOT - 1)) * KOb + t,
                  shb[t]);
}

// =====================================================================
// K2: fused Hbins-reduce + Wsoft/Wmean (redundant per block, L2-hot)
// + per-row: R_edges -> A1 -> entropy -> U, m; also chi.
// =====================================================================
__global__ __launch_bounds__(256) void k_row1(const float* __restrict__ bins,
                                              float* __restrict__ ws,
                                              float* __restrict__ out_u) {
    __shared__ float sbins[2 * KOb], sHB[BB * KOb], swsoft[BB * KOb], swmean[KOb];
    const int t = threadIdx.x;
    if (t < 2 * KOb) sbins[t] = bins[t];
    if (t >= 64 && t < 64 + BB * KOb) sHB[t - 64] = 0.f;
    __syncthreads();

    // reduce 2*64*32 partials: 512 tasks, 2 per thread
    #pragma unroll
    for (int rep = 0; rep < 2; ++rep) {
        const int task = t + 256 * rep;
        const int bo = task & 63;          // (b,o) pair
        const int sg = task >> 6;          // slot group 0..7
        float ps = 0.f;
        #pragma unroll
        for (int s = 0; s < 8; ++s)
            ps += ws[WS_HBP + (bo >> 5) * (NSLOT * KOb) + (sg * 8 + s) * KOb + (bo & 31)];
        atomicAdd(&sHB[bo], ps);
    }
    __syncthreads();
    if (t < BB * KOb) {                    // wave 0: softmax per batch-half
        const float h = 8.0f * sHB[t];
        float mx = h;
        #pragma unroll
        for (int m = 16; m >= 1; m >>= 1) mx = fmaxf(mx, __shfl_xor(mx, m));
        const float e = __expf(h - mx);
        float s = e;
        #pragma unroll
        for (int m = 16; m >= 1; m >>= 1) s += __shfl_xor(s, m);
        swsoft[t] = e / s;
    }
    if (t < KOb) swmean[t] = 0.5f * (swsoft[t] + swsoft[KOb + t]); // same wave, DS in-order
    __syncthreads();

    const int wv = t >> 6, lane = t & 63;
    const int R = blockIdx.x * 4 + wv;
    const int b = R >> 12;
    const int r = R & (NN - 1);
    const bool act = lane < 32;
    const int k = lane;

    float val = 0.f, Redge = 0.f, chi = 0.f;
    if (act) {
        val = ws[WS_VALS + (size_t)R * KK + k];
        const int c = ((int*)(ws + WS_IDX))[(size_t)R * KK + k];
        const float dx0 = (float)((c & 63) - (r & 63));
        const float dy0 = (float)((c >> 6) - (r >> 6));
        float racc = 0.f, cacc = 0.f;
        for (int o = 0; o < KOb; ++o) {
            const float dx = dx0 - sbins[2 * o], dy = dy0 - sbins[2 * o + 1];
            const float kap = __expf(-(dx * dx + dy * dy) * (1.0f / 4.5f));
            racc += swsoft[b * KOb + o] * kap;
            cacc += swmean[o] * kap;
        }
        Redge = 0.001f + racc;
        chi = cacc;
    }
    const float tilde = act ? val * Redge : 0.f;
    float s = tilde;
    #pragma unroll
    for (int m = 16; m >= 1; m >>= 1) s += __shfl_xor(s, m);
    const float a1 = tilde / (s + EPS);

    const float z = act ? 10.f * a1 : -1e30f;
    float mz = z;
    #pragma unroll
    for (int m = 16; m >= 1; m >>= 1) mz = fmaxf(mz, __shfl_xor(mz, m));
    const float e = act ? __expf(z - mz) : 0.f;
    float se = e;
    #pragma unroll
    for (int m = 16; m >= 1; m >>= 1) se += __shfl_xor(se, m);
    const float p = e / se;
    const float ent_t = act ? -p * __logf(p + EPS) : 0.f;
    float ent = ent_t;
    #pragma unroll
    for (int m = 16; m >= 1; m >>= 1) ent += __shfl_xor(ent, m);
    const float U = 1.f / (1.f + __expf(ent));

    if (act) {
        ws[WS_A1  + (size_t)R * KK + k] = a1;
        ws[WS_CHI + (size_t)R * KK + k] = chi;
    }
    if (lane == 0) { out_u[R] = U; ws[WS_M + R] = 1.f - U; }
}

// =====================================================================
// K3: fused row2 + dense write. One block per row: wave 0 does the
// math (hatA -> A2_edges -> dv, q), whole block streams the dense row.
// Also zero-fills WS_TEV (blocks 0..31).
// =====================================================================
__global__ __launch_bounds__(256) void k_row2d(float* __restrict__ ws,
                                               float* __restrict__ outA2) {
    __shared__ float srow[NN];
    __shared__ float sdv[KK];
    __shared__ int   sidx[KK];
    const int R = blockIdx.x;
    const int b = R >> 12;
    const int r = R & (NN - 1);
    const int t = threadIdx.x;

    const int gid = blockIdx.x * 256 + t;
    if (gid < BB * NN) ws[WS_TEV + gid] = 0.f;

    float4* s4 = (float4*)srow;
    const float4 z4 = make_float4(0.f, 0.f, 0.f, 0.f);
    #pragma unroll
    for (int i = 0; i < 4; ++i) s4[t + 256 * i] = z4;

    if (t < 64) {                          // wave 0 math
        const int lane = t;
        const bool act = lane < 32;
        const int k = lane;
        const float mi = ws[WS_M + R];
        float a1 = 0.f; int c = 0; float mj = 0.f;
        if (act) {
            a1 = ws[WS_A1 + (size_t)R * KK + k];
            c = ((int*)(ws + WS_IDX))[(size_t)R * KK + k];
            mj = ws[WS_M + b * NN + c];
        }
        const float hat = act ? mi * a1 * mj : 0.f;
        float S = hat;
        #pragma unroll
        for (int m = 16; m >= 1; m >>= 1) S += __shfl_xor(S, m);
        const float a2e = hat / (S + EPS);
        float S2 = a2e;
        #pragma unroll
        for (int m = 16; m >= 1; m >>= 1) S2 += __shfl_xor(S2, m);
        const float dv = a2e / (S2 + EPS);

        const float z = act ? 8.f * a2e : -1e30f;
        float mz = z;
        #pragma unroll
        for (int m = 16; m >= 1; m >>= 1) mz = fmaxf(mz, __shfl_xor(mz, m));
        const float e = act ? __expf(z - mz) : 0.f;
        float se = e;
        #pragma unroll
        for (int m = 16; m >= 1; m >>= 1) se += __shfl_xor(se, m);
        const float wl = e / se;
        const float chi = act ? ws[WS_CHI + (size_t)R * KK + k] : 0.f;
        float q = act ? wl * chi : 0.f;
        #pragma unroll
        for (int m = 16; m >= 1; m >>= 1) q += __shfl_xor(q, m);
        if (lane == 0) ws[WS_Q + R] = q;

        if (act) {
            ws[WS_A2 + (size_t)R * KK + k] = dv;
            sdv[k] = dv;
            sidx[k] = c;
        }
    }
    __syncthreads();
    if (t < KK) srow[sidx[t]] = sdv[t];
    __syncthreads();
    float4* o4 = (float4*)(outA2 + (size_t)b * NN * NN + (size_t)r * NN);
    #pragma unroll
    for (int i = 0; i < 4; ++i) o4[t + 256 * i] = s4[t + 256 * i];
}

// =====================================================================
// K4: directional evidence (rev values gathered from dense output).
// =====================================================================
__global__ __launch_bounds__(256) void k_dir(float* __restrict__ ws,
                                             const float* __restrict__ A2d) {
    const int t = threadIdx.x;
    const int wv = t >> 6, lane = t & 63;
    const int R = blockIdx.x * 4 + wv;
    const int b = R >> 12;
    const int r = R & (NN - 1);
    const bool act = lane < 32;
    const int k = lane;

    float a = 0.f; int c = r;
    if (act) {
        a = ws[WS_A2 + (size_t)R * KK + k];
        c = ((int*)(ws + WS_IDX))[(size_t)R * KK + k];
    }
    float pdir = 0.f;
    if (act && c != r) {
        const float arev = A2d[(size_t)b * NN * NN + (size_t)c * NN + r];
        const float ef = __expf(8.f * a), er = __expf(8.f * arev);
        pdir = ef / (ef + er + EPS);
    }
    float s = a * pdir;
    #pragma unroll
    for (int m = 16; m >= 1; m >>= 1) s += __shfl_xor(s, m);
    if (lane == 0) ws[WS_SEV + R] = s;
    if (act) atomicAdd(ws + WS_TEV + b * NN + c, a * (1.f - pdir));
}

// =====================================================================
// K5: fused pi_src/pi_tgt + 5x5 gaussian smoothing + sigmoid.
// =====================================================================
__global__ void k_tail(const float* __restrict__ ws, const float* __restrict__ kern,
                       float* __restrict__ out_psrc, float* __restrict__ out_ptgt,
                       float* __restrict__ out_map) {
    const int i = blockIdx.x * 256 + threadIdx.x;
    const float s = ws[WS_SEV + i], tv = ws[WS_TEV + i];
    const float ps = s / (s + tv + EPS);
    out_psrc[i] = ps;
    out_ptgt[i] = 1.f - ps;

    const int b = i >> 12;
    const int pix = i & 4095;
    const int y = pix >> 6, x = pix & 63;
    float acc = 0.f;
    #pragma unroll
    for (int ky = 0; ky < 5; ++ky) {
        const int yy = y + ky - 2;
        if (yy < 0 || yy >= 64) continue;
        #pragma unroll
        for (int kx = 0; kx < 5; ++kx) {
            const int xx = x + kx - 2;
            if (xx < 0 || xx >= 64) continue;
            acc += ws[WS_Q + b * 4096 + yy * 64 + xx] * kern[ky * 5 + kx];
        }
    }
    out_map[i] = 1.f / (1.f + __expf(-acc));
}

extern "C" void kernel_launch(void* const* d_in, const int* in_sizes, int n_in,
                              void* d_out, int out_size, void* d_ws, size_t ws_size,
                              hipStream_t stream) {
    const float* A0   = (const float*)d_in[1];
    const float* bins = (const float*)d_in[3];
    const float* kern = (const float*)d_in[4];
    float* out = (float*)d_out;
    float* ws  = (float*)d_ws;

    hipMemsetAsync(ws + WS_HBP, 0, BB * NSLOT * KOb * sizeof(float), stream);

    k_topk <<<BB * NN / 4,   256, 0, stream>>>(A0, bins, ws);
    k_row1 <<<BB * NN / 4,   256, 0, stream>>>(bins, ws, out + OUT_U);
    k_row2d<<<BB * NN,       256, 0, stream>>>(ws, out);
    k_dir  <<<BB * NN / 4,   256, 0, stream>>>(ws, out);
    k_tail <<<BB * NN / 256, 256, 0, stream>>>(ws, kern,
                                               out + OUT_PSRC, out + OUT_PTGT,
                                               out + OUT_MAP);
}

// Round 5
// 296.763 us; speedup vs baseline: 1.8509x; 1.1253x over previous
//
#include <hip/hip_runtime.h>
#include <math.h>

#define NN 4096
#define KK 32
#define KOb 32
#define BB 2
#define NSLOT 64   // Hbins partial slots (bounds global atomic contention)

constexpr float EPS = 1e-6f;

// ---- workspace layout (in float elements) ----
#define WS_VALS   0                          // B*N*K floats
#define WS_IDX    (WS_VALS + BB*NN*KK)       // B*N*K ints
#define WS_HBP    (WS_IDX + BB*NN*KK)        // B*NSLOT*KO partials (memset 0)
#define WS_A1     (WS_HBP + BB*NSLOT*KOb)    // B*N*K
#define WS_M      (WS_A1 + BB*NN*KK)         // B*N
#define WS_CHI    (WS_M + BB*NN)             // B*N*K
#define WS_A2     (WS_CHI + BB*NN*KK)        // B*N*K
#define WS_SEV    (WS_A2 + BB*NN*KK)         // B*N
#define WS_TEV    (WS_SEV + BB*NN)           // B*N (zeroed in k_row2d)
#define WS_Q      (WS_TEV + BB*NN)           // B*N

// ---- output layout (float elements) ----
#define OUT_A2   0
#define OUT_U    ((size_t)BB*NN*NN)
#define OUT_PSRC (OUT_U + BB*NN)
#define OUT_PTGT (OUT_PSRC + BB*NN)
#define OUT_MAP  (OUT_PTGT + BB*NN)

__device__ __forceinline__ unsigned int fkey(float x) {
    unsigned int u = __float_as_uint(x);
    return u ^ ((unsigned int)((int)u >> 31) | 0x80000000u);
}
__device__ __forceinline__ float key2f(unsigned int k) {
    unsigned int u = (k & 0x80000000u) ? (k ^ 0x80000000u) : ~k;
    return __uint_as_float(u);
}

// =====================================================================
// K1: per-row top-32, ONE 256-thread BLOCK per row (high occupancy,
// short per-wave critical path). 16 keys/lane in registers, coalesced.
// Block-level threshold search (LDS count reduce), block prefix
// compaction of <=64 candidates, wave0 rank-selects, then the whole
// block computes the fused Hbins contribution (32 edges x 32 bins
// distributed 4 tasks/thread, shuffle-reduced, conflict-free atomics).
// =====================================================================
__global__ __launch_bounds__(256) void k_topk(const float* __restrict__ A0,
                                              const float* __restrict__ bins,
                                              float* __restrict__ ws) {
    __shared__ float sbins[2 * KOb];
    __shared__ int   scnt[4];
    __shared__ int   swtot[4];
    __shared__ unsigned long long cand[64];
    __shared__ float selv[KK], seldx[KK], seldy[KK];
    __shared__ float shb[KOb];

    const int t = threadIdx.x;
    const int wv = t >> 6, lane = t & 63;
    const int R = blockIdx.x;
    const int b = R >> 12;
    const int r = R & (NN - 1);

    if (t < 2 * KOb) sbins[t] = bins[t];
    if (t < KOb) shb[t] = 0.f;

    // coalesced: thread t reads float4 #(i*256+t); elem of key[4i+c] = i*1024 + t*4 + c
    const float4* row4 = (const float4*)(A0 + (size_t)R * NN);
    unsigned int key[16];
    #pragma unroll
    for (int i = 0; i < 4; ++i) {
        const float4 f = row4[i * 256 + t];
        key[4 * i + 0] = fkey(f.x);
        key[4 * i + 1] = fkey(f.y);
        key[4 * i + 2] = fkey(f.z);
        key[4 * i + 3] = fkey(f.w);
    }

    // ---- block-uniform threshold search: 32 <= count(key > lo) <= 64 ----
    unsigned int lo = 0u, hi = 0xFFFFFFFFu;
    int cnt = NN, it = 0;
    while (cnt > 64) {
        unsigned int mid;
        if (it == 0)      mid = 0xBF7E0000u;   // fkey(0.9921875) ~ E[cnt]=32
        else if (it == 1) mid = 0xBF7C4000u;   // fkey(0.98535)  ~ E[cnt]=60
        else              mid = lo + ((hi - lo) >> 1);
        if (mid <= lo || mid >= hi) mid = lo + ((hi - lo) >> 1);
        if (mid == lo) break;
        int cl = 0;
        #pragma unroll
        for (int j = 0; j < 16; ++j) cl += (key[j] > mid) ? 1 : 0;
        int c = cl;
        #pragma unroll
        for (int m = 32; m >= 1; m >>= 1) c += __shfl_xor(c, m);
        if (lane == 0) scnt[wv] = c;
        __syncthreads();
        const int ctot = scnt[0] + scnt[1] + scnt[2] + scnt[3];
        __syncthreads();
        if (ctot >= KK) { lo = mid; cnt = ctot; } else hi = mid;
        if (++it > 48) break;
    }

    // ---- block prefix compaction of candidates {key > lo} ----
    int cl = 0;
    #pragma unroll
    for (int j = 0; j < 16; ++j) cl += (key[j] > lo) ? 1 : 0;
    int inc = cl;
    #pragma unroll
    for (int m = 1; m < 64; m <<= 1) {
        const int o = __shfl_up(inc, m);
        if (lane >= m) inc += o;
    }
    if (lane == 63) swtot[wv] = inc;
    __syncthreads();
    int off = inc - cl;                        // exclusive within wave
    #pragma unroll
    for (int w = 0; w < 4; ++w) if (w < wv) off += swtot[w];
    const int nc0 = swtot[0] + swtot[1] + swtot[2] + swtot[3];
    const int ncand = (nc0 < 64) ? nc0 : 64;

    int slot = off;
    #pragma unroll
    for (int j = 0; j < 16; ++j) {
        if (key[j] > lo && slot < 64) {
            const unsigned int gidx = (unsigned int)((j >> 2) * 1024 + t * 4 + (j & 3));
            cand[slot] = ((unsigned long long)key[j] << 32)
                       | (unsigned long long)(4095u - gidx);
            ++slot;
        }
    }
    __syncthreads();

    // ---- wave 0: rank selection + emit; packed u64 gives exact tie-break ----
    if (t < 64) {
        const unsigned long long cd = (t < ncand) ? cand[t] : 0ull;
        int rank = 0;
        #pragma unroll
        for (int i = 0; i < 64; ++i) {
            const unsigned long long o = __shfl(cd, i);
            rank += (o > cd) ? 1 : 0;
        }
        if (t < ncand && rank < KK) {
            const float val = key2f((unsigned int)(cd >> 32));
            const int gidx = 4095 - (int)(cd & 0xFFFull);
            ws[WS_VALS + (size_t)R * KK + rank] = val;
            ((int*)(ws + WS_IDX))[(size_t)R * KK + rank] = gidx;
            selv[rank]  = val;
            seldx[rank] = (float)((gidx & 63) - (r & 63));
            seldy[rank] = (float)((gidx >> 6) - (r >> 6));
        }
    }
    __syncthreads();

    // ---- fused Hbins: 32 edges x 32 bins = 1024 tasks over 256 threads ----
    const int e = t >> 3;                       // edge 0..31
    const float v = selv[e], dx0 = seldx[e], dy0 = seldy[e];
    #pragma unroll
    for (int jj = 0; jj < 4; ++jj) {
        const int o = (lane & 7) * 4 + jj;      // bin, constant across xor-8/16/32 group
        const float dx = dx0 - sbins[2 * o], dy = dy0 - sbins[2 * o + 1];
        float contrib = v * __expf(-(dx * dx + dy * dy) * (1.0f / 4.5f));
        contrib += __shfl_xor(contrib, 8);
        contrib += __shfl_xor(contrib, 16);
        contrib += __shfl_xor(contrib, 32);
        if ((lane >> 3) == 0) atomicAdd(&shb[o], contrib);
    }
    __syncthreads();
    if (t < KOb)
        atomicAdd(ws + WS_HBP + b * (NSLOT * KOb) + (R & (NSLOT - 1)) * KOb + t,
                  shb[t]);
}

// =====================================================================
// K2: fused Hbins-reduce + Wsoft/Wmean (redundant per block, L2-hot)
// + per-row: R_edges -> A1 -> entropy -> U, m; also chi.
// =====================================================================
__global__ __launch_bounds__(256) void k_row1(const float* __restrict__ bins,
                                              float* __restrict__ ws,
                                              float* __restrict__ out_u) {
    __shared__ float sbins[2 * KOb], sHB[BB * KOb], swsoft[BB * KOb], swmean[KOb];
    const int t = threadIdx.x;
    if (t < 2 * KOb) sbins[t] = bins[t];
    if (t >= 64 && t < 64 + BB * KOb) sHB[t - 64] = 0.f;
    __syncthreads();

    #pragma unroll
    for (int rep = 0; rep < 2; ++rep) {
        const int task = t + 256 * rep;
        const int bo = task & 63;
        const int sg = task >> 6;
        float ps = 0.f;
        #pragma unroll
        for (int s = 0; s < 8; ++s)
            ps += ws[WS_HBP + (bo >> 5) * (NSLOT * KOb) + (sg * 8 + s) * KOb + (bo & 31)];
        atomicAdd(&sHB[bo], ps);
    }
    __syncthreads();
    if (t < BB * KOb) {
        const float h = 8.0f * sHB[t];
        float mx = h;
        #pragma unroll
        for (int m = 16; m >= 1; m >>= 1) mx = fmaxf(mx, __shfl_xor(mx, m));
        const float e = __expf(h - mx);
        float s = e;
        #pragma unroll
        for (int m = 16; m >= 1; m >>= 1) s += __shfl_xor(s, m);
        swsoft[t] = e / s;
    }
    if (t < KOb) swmean[t] = 0.5f * (swsoft[t] + swsoft[KOb + t]);
    __syncthreads();

    const int wv = t >> 6, lane = t & 63;
    const int R = blockIdx.x * 4 + wv;
    const int b = R >> 12;
    const int r = R & (NN - 1);
    const bool act = lane < 32;
    const int k = lane;

    float val = 0.f, Redge = 0.f, chi = 0.f;
    if (act) {
        val = ws[WS_VALS + (size_t)R * KK + k];
        const int c = ((int*)(ws + WS_IDX))[(size_t)R * KK + k];
        const float dx0 = (float)((c & 63) - (r & 63));
        const float dy0 = (float)((c >> 6) - (r >> 6));
        float racc = 0.f, cacc = 0.f;
        for (int o = 0; o < KOb; ++o) {
            const float dx = dx0 - sbins[2 * o], dy = dy0 - sbins[2 * o + 1];
            const float kap = __expf(-(dx * dx + dy * dy) * (1.0f / 4.5f));
            racc += swsoft[b * KOb + o] * kap;
            cacc += swmean[o] * kap;
        }
        Redge = 0.001f + racc;
        chi = cacc;
    }
    const float tilde = act ? val * Redge : 0.f;
    float s = tilde;
    #pragma unroll
    for (int m = 16; m >= 1; m >>= 1) s += __shfl_xor(s, m);
    const float a1 = tilde / (s + EPS);

    const float z = act ? 10.f * a1 : -1e30f;
    float mz = z;
    #pragma unroll
    for (int m = 16; m >= 1; m >>= 1) mz = fmaxf(mz, __shfl_xor(mz, m));
    const float e = act ? __expf(z - mz) : 0.f;
    float se = e;
    #pragma unroll
    for (int m = 16; m >= 1; m >>= 1) se += __shfl_xor(se, m);
    const float p = e / se;
    const float ent_t = act ? -p * __logf(p + EPS) : 0.f;
    float ent = ent_t;
    #pragma unroll
    for (int m = 16; m >= 1; m >>= 1) ent += __shfl_xor(ent, m);
    const float U = 1.f / (1.f + __expf(ent));

    if (act) {
        ws[WS_A1  + (size_t)R * KK + k] = a1;
        ws[WS_CHI + (size_t)R * KK + k] = chi;
    }
    if (lane == 0) { out_u[R] = U; ws[WS_M + R] = 1.f - U; }
}

// =====================================================================
// K3: fused row2 + dense write. One block per row: wave 0 does the
// math (hatA -> A2_edges -> dv, q), whole block streams the dense row.
// Also zero-fills WS_TEV (blocks 0..31).
// =====================================================================
__global__ __launch_bounds__(256) void k_row2d(float* __restrict__ ws,
                                               float* __restrict__ outA2) {
    __shared__ float srow[NN];
    __shared__ float sdv[KK];
    __shared__ int   sidx[KK];
    const int R = blockIdx.x;
    const int b = R >> 12;
    const int r = R & (NN - 1);
    const int t = threadIdx.x;

    const int gid = blockIdx.x * 256 + t;
    if (gid < BB * NN) ws[WS_TEV + gid] = 0.f;

    float4* s4 = (float4*)srow;
    const float4 z4 = make_float4(0.f, 0.f, 0.f, 0.f);
    #pragma unroll
    for (int i = 0; i < 4; ++i) s4[t + 256 * i] = z4;

    if (t < 64) {
        const int lane = t;
        const bool act = lane < 32;
        const int k = lane;
        const float mi = ws[WS_M + R];
        float a1 = 0.f; int c = 0; float mj = 0.f;
        if (act) {
            a1 = ws[WS_A1 + (size_t)R * KK + k];
            c = ((int*)(ws + WS_IDX))[(size_t)R * KK + k];
            mj = ws[WS_M + b * NN + c];
        }
        const float hat = act ? mi * a1 * mj : 0.f;
        float S = hat;
        #pragma unroll
        for (int m = 16; m >= 1; m >>= 1) S += __shfl_xor(S, m);
        const float a2e = hat / (S + EPS);
        float S2 = a2e;
        #pragma unroll
        for (int m = 16; m >= 1; m >>= 1) S2 += __shfl_xor(S2, m);
        const float dv = a2e / (S2 + EPS);

        const float z = act ? 8.f * a2e : -1e30f;
        float mz = z;
        #pragma unroll
        for (int m = 16; m >= 1; m >>= 1) mz = fmaxf(mz, __shfl_xor(mz, m));
        const float e = act ? __expf(z - mz) : 0.f;
        float se = e;
        #pragma unroll
        for (int m = 16; m >= 1; m >>= 1) se += __shfl_xor(se, m);
        const float wl = e / se;
        const float chi = act ? ws[WS_CHI + (size_t)R * KK + k] : 0.f;
        float q = act ? wl * chi : 0.f;
        #pragma unroll
        for (int m = 16; m >= 1; m >>= 1) q += __shfl_xor(q, m);
        if (lane == 0) ws[WS_Q + R] = q;

        if (act) {
            ws[WS_A2 + (size_t)R * KK + k] = dv;
            sdv[k] = dv;
            sidx[k] = c;
        }
    }
    __syncthreads();
    if (t < KK) srow[sidx[t]] = sdv[t];
    __syncthreads();
    float4* o4 = (float4*)(outA2 + (size_t)b * NN * NN + (size_t)r * NN);
    #pragma unroll
    for (int i = 0; i < 4; ++i) o4[t + 256 * i] = s4[t + 256 * i];
}

// =====================================================================
// K4: directional evidence — reverse value found by searching row c's
// 32 indices in the L2-resident edge arrays (2 MB), not the 134 MB
// dense matrix.
// =====================================================================
__global__ __launch_bounds__(256) void k_dir(float* __restrict__ ws) {
    const int t = threadIdx.x;
    const int wv = t >> 6, lane = t & 63;
    const int R = blockIdx.x * 4 + wv;
    const int b = R >> 12;
    const int r = R & (NN - 1);
    const bool act = lane < 32;
    const int k = lane;

    float a = 0.f; int c = r;
    if (act) {
        a = ws[WS_A2 + (size_t)R * KK + k];
        c = ((int*)(ws + WS_IDX))[(size_t)R * KK + k];
    }
    float pdir = 0.f;
    if (act && c != r) {
        const int4* irow = (const int4*)((const int*)(ws + WS_IDX)
                                         + (size_t)(b * NN + c) * KK);
        int p = -1;
        #pragma unroll
        for (int q = 0; q < 8; ++q) {
            const int4 i4 = irow[q];
            if (i4.x == r) p = q * 4 + 0;
            if (i4.y == r) p = q * 4 + 1;
            if (i4.z == r) p = q * 4 + 2;
            if (i4.w == r) p = q * 4 + 3;
        }
        const float arev = (p >= 0) ? ws[WS_A2 + (size_t)(b * NN + c) * KK + p] : 0.f;
        const float ef = __expf(8.f * a), er = __expf(8.f * arev);
        pdir = ef / (ef + er + EPS);
    }
    float s = a * pdir;
    #pragma unroll
    for (int m = 16; m >= 1; m >>= 1) s += __shfl_xor(s, m);
    if (lane == 0) ws[WS_SEV + R] = s;
    if (act) atomicAdd(ws + WS_TEV + b * NN + c, a * (1.f - pdir));
}

// =====================================================================
// K5: fused pi_src/pi_tgt + 5x5 gaussian smoothing + sigmoid.
// =====================================================================
__global__ void k_tail(const float* __restrict__ ws, const float* __restrict__ kern,
                       float* __restrict__ out_psrc, float* __restrict__ out_ptgt,
                       float* __restrict__ out_map) {
    const int i = blockIdx.x * 256 + threadIdx.x;
    const float s = ws[WS_SEV + i], tv = ws[WS_TEV + i];
    const float ps = s / (s + tv + EPS);
    out_psrc[i] = ps;
    out_ptgt[i] = 1.f - ps;

    const int b = i >> 12;
    const int pix = i & 4095;
    const int y = pix >> 6, x = pix & 63;
    float acc = 0.f;
    #pragma unroll
    for (int ky = 0; ky < 5; ++ky) {
        const int yy = y + ky - 2;
        if (yy < 0 || yy >= 64) continue;
        #pragma unroll
        for (int kx = 0; kx < 5; ++kx) {
            const int xx = x + kx - 2;
            if (xx < 0 || xx >= 64) continue;
            acc += ws[WS_Q + b * 4096 + yy * 64 + xx] * kern[ky * 5 + kx];
        }
    }
    out_map[i] = 1.f / (1.f + __expf(-acc));
}

extern "C" void kernel_launch(void* const* d_in, const int* in_sizes, int n_in,
                              void* d_out, int out_size, void* d_ws, size_t ws_size,
                              hipStream_t stream) {
    const float* A0   = (const float*)d_in[1];
    const float* bins = (const float*)d_in[3];
    const float* kern = (const float*)d_in[4];
    float* out = (float*)d_out;
    float* ws  = (float*)d_ws;

    hipMemsetAsync(ws + WS_HBP, 0, BB * NSLOT * KOb * sizeof(float), stream);

    k_topk <<<BB * NN,       256, 0, stream>>>(A0, bins, ws);
    k_row1 <<<BB * NN / 4,   256, 0, stream>>>(bins, ws, out + OUT_U);
    k_row2d<<<BB * NN,       256, 0, stream>>>(ws, out);
    k_dir  <<<BB * NN / 4,   256, 0, stream>>>(ws);
    k_tail <<<BB * NN / 256, 256, 0, stream>>>(ws, kern,
                                               out + OUT_PSRC, out + OUT_PTGT,
                                               out + OUT_MAP);
}